// Round 8
// baseline (179.126 us; speedup 1.0000x reference)
//
#include <hip/hip_runtime.h>
#include <math.h>

// RiemannianMetric: g[b,s,i,j] = sum_r tanh(x·W[r]+b[r])^2 A[r,i]A[r,j] + lam*I
// B=2 S=1024 DIM=256 RANK=32. Output 537 MB f32 -> store floor ~80us @6.7TB/s.
// R8: A/B vs R7 — ONLY change: plain cached stores instead of nontemporal.
// Theory: nt (no-allocate) defeats L2 write-back coalescing -> ~4 TB/s cap across
// R1/R5/R6/R7; fillBuffer (plain stores) hits 6.8 TB/s on this same buffer.

constexpr int DIM  = 256;
constexpr int RANK = 32;

typedef float f32x4 __attribute__((ext_vector_type(4)));
typedef short s16x8 __attribute__((ext_vector_type(8))); // 8 bf16 = 4 VGPR

static __device__ __forceinline__ unsigned short f2bf(float f) {
    unsigned int u = __builtin_bit_cast(unsigned int, f);
    u = (u + 0x7FFFu + ((u >> 16) & 1u)) >> 16; // RNE
    return (unsigned short)u;
}

__global__ __launch_bounds__(256, 2) void riemannian_metric_kernel(
    const float* __restrict__ x,          // [B*S, DIM]
    const float* __restrict__ A,          // [RANK, DIM]
    const float* __restrict__ log_lambda, // [1]
    const float* __restrict__ W,          // [RANK, DIM]
    const float* __restrict__ bvec,       // [RANK]
    float* __restrict__ out)              // [B*S, DIM, DIM]
{
    __shared__ float xs[DIM];
    __shared__ float sw[RANK];
    __shared__ alignas(16) unsigned short vt[4][DIM][8]; // [k>>3][j][k&7] bf16, 16KB
    __shared__ alignas(16) float stage[4][16 * 128];     // per-wave 8KB transpose buf

    const int tid  = threadIdx.x;
    const int pos  = blockIdx.x;
    const int lane = tid & 63;
    const int rs   = tid >> 6;   // wave id: rows 64rs..64rs+63

    xs[tid] = x[(size_t)pos * DIM + tid];
    __syncthreads();

    // sw[r] = tanh(x·W[r]+b[r]) — signed; folded into BOTH factors -> squares
    {
        const int r = tid >> 3, seg = tid & 7;
        const f32x4* wr4 = (const f32x4*)(W + r * DIM + seg * 32);
        const f32x4* xr4 = (const f32x4*)(xs + seg * 32);
        float dot = 0.f;
        #pragma unroll
        for (int qq = 0; qq < 8; ++qq) {
            f32x4 wv = wr4[qq], xv = xr4[qq];
            dot = fmaf(wv.x, xv.x, dot);
            dot = fmaf(wv.y, xv.y, dot);
            dot = fmaf(wv.z, xv.z, dot);
            dot = fmaf(wv.w, xv.w, dot);
        }
        dot += __shfl_xor(dot, 1);
        dot += __shfl_xor(dot, 2);
        dot += __shfl_xor(dot, 4);
        if (seg == 0) sw[r] = tanhf(dot + bvec[r]);
    }
    __syncthreads();

    // build V^T slabs: vt[kg][j][e] = bf16(sw[8kg+e] * A[8kg+e][j]), j = tid
    #pragma unroll
    for (int g = 0; g < 4; ++g) {
        s16x8 pk;
        #pragma unroll
        for (int e = 0; e < 8; ++e) {
            const int k = g * 8 + e;
            pk[e] = (short)f2bf(sw[k] * A[k * DIM + tid]);
        }
        *(s16x8*)&vt[g][tid][0] = pk;
    }
    __syncthreads();

    // fragment loads: lane (kg=lane>>4, cl=lane&15) holds k = kg*8+e of col tile*16+cl
    const int kg = lane >> 4, cl = lane & 15;
    const int q  = kg;           // C-frag row-group alias
    s16x8 bfr[16];
    #pragma unroll
    for (int u = 0; u < 16; ++u)
        bfr[u] = *(const s16x8*)&vt[kg][u * 16 + cl][0];
    s16x8 afr[4];
    #pragma unroll
    for (int t = 0; t < 4; ++t)
        afr[t] = *(const s16x8*)&vt[kg][rs * 64 + t * 16 + cl][0];

    const float lam = expf(log_lambda[0]);
    const bool on_diag_lane = (q == (cl >> 2));
    const int  diag_slot    = cl & 3;

    float* sbuf = stage[rs];
    // stage addressing: idx = row*128 + col, swizzle ^((row&7)<<2) (float units;
    // = byte ^ ((row&7)<<4) -> beat-conflict-free for both b128 write and read)
    const int wbase = cl * 128 + 4 * q;      // write: row=cl, col=uu*16+4q
    const int wswz  = (cl & 7) << 2;
    const int rrow0 = lane >> 5;             // read: 2 rows per instruction
    const int rcol  = (lane & 31) * 4;

    float* gbase = out + (size_t)pos * DIM * DIM;

    #pragma unroll 1
    for (int t = 0; t < 4; ++t) {
        #pragma unroll 1
        for (int half = 0; half < 2; ++half) {
            // 8 MFMAs -> 16x128 sub-tile into swizzled stage
            #pragma unroll
            for (int uu = 0; uu < 8; ++uu) {
                const int u = half * 8 + uu;
                f32x4 acc = (f32x4)(0.f);
                acc = __builtin_amdgcn_mfma_f32_16x16x32_bf16(bfr[u], afr[t], acc, 0, 0, 0);
                if (u == rs * 4 + t && on_diag_lane) // diagonal tile of G
                    acc[diag_slot] += lam;
                *(f32x4*)&sbuf[(wbase + uu * 16) ^ wswz] = acc;
            }
            // read back 2 full rows per instruction -> contiguous 512B-segment stores
            #pragma unroll
            for (int m = 0; m < 8; ++m) {
                const int row = 2 * m + rrow0;
                f32x4 v = *(const f32x4*)&sbuf[(row * 128 + rcol) ^ ((row & 7) << 2)];
                float* gp = gbase + (size_t)(rs * 64 + t * 16 + row) * DIM
                                  + half * 128 + rcol;
                *(f32x4*)gp = v; // PLAIN cached store (the only change vs R7)
            }
        }
    }
}

extern "C" void kernel_launch(void* const* d_in, const int* in_sizes, int n_in,
                              void* d_out, int out_size, void* d_ws, size_t ws_size,
                              hipStream_t stream) {
    const float* x          = (const float*)d_in[0];
    const float* A          = (const float*)d_in[1];
    const float* log_lambda = (const float*)d_in[2];
    const float* W          = (const float*)d_in[3];
    const float* bvec       = (const float*)d_in[4];
    float* out              = (float*)d_out;

    const int n_pos = in_sizes[0] / DIM; // B*S = 2048
    riemannian_metric_kernel<<<n_pos, 256, 0, stream>>>(x, A, log_lambda, W, bvec, out);
}

// Round 9
// 127.267 us; speedup vs baseline: 1.4075x; 1.4075x over previous
//
#include <hip/hip_runtime.h>
#include <math.h>

// RiemannianMetric: g[b,s,i,j] = sum_r tanh(x·W[r]+b[r])^2 A[r,i]A[r,j] + lam*I
// B=2 S=1024 DIM=256 RANK=32. Output 512 MiB f32 -> store floor ~80us @6.7TB/s.
// R9: two-kernel split. K1 (~10us) writes V^T = tanh-scaled A (bf16, 32MB) to d_ws.
// K2 is a BARRIER-FREE streamer: per wave, frags from L1-hot V^T -> 64 MFMA ->
// wave-private 8KB LDS transpose -> nt stores (R7's validated 512B-seg pattern).
// LDS 32KB/block -> 5 blocks/CU; no __syncthreads anywhere in K2 -> store-issue
// overlap limited only by the memory system, not by intra-block coupling.

constexpr int DIM  = 256;
constexpr int RANK = 32;

typedef float f32x4 __attribute__((ext_vector_type(4)));
typedef short s16x8 __attribute__((ext_vector_type(8))); // 8 bf16 = 4 VGPR

static __device__ __forceinline__ unsigned short f2bf(float f) {
    unsigned int u = __builtin_bit_cast(unsigned int, f);
    u = (u + 0x7FFFu + ((u >> 16) & 1u)) >> 16; // RNE
    return (unsigned short)u;
}

// ---------------- Kernel 1: V^T build -> d_ws --------------------------------
// layout: vt_g[pos][kg][j][e] (kg=k>>3, e=k&7), u16 bf16. 2048*4*256*8*2B = 32MB.
__global__ __launch_bounds__(256) void build_vt_kernel(
    const float* __restrict__ x, const float* __restrict__ A,
    const float* __restrict__ W, const float* __restrict__ bvec,
    unsigned short* __restrict__ vt_g)
{
    __shared__ float xs[DIM];
    __shared__ float sw[RANK];
    const int tid = threadIdx.x, pos = blockIdx.x;

    xs[tid] = x[(size_t)pos * DIM + tid];
    __syncthreads();

    { // sw[r] = tanh(x·W[r]+b[r]) — 8 lanes per rank, shfl-reduced
        const int r = tid >> 3, seg = tid & 7;
        const f32x4* wr4 = (const f32x4*)(W + r * DIM + seg * 32);
        const f32x4* xr4 = (const f32x4*)(xs + seg * 32);
        float dot = 0.f;
        #pragma unroll
        for (int qq = 0; qq < 8; ++qq) {
            f32x4 wv = wr4[qq], xv = xr4[qq];
            dot = fmaf(wv.x, xv.x, dot);
            dot = fmaf(wv.y, xv.y, dot);
            dot = fmaf(wv.z, xv.z, dot);
            dot = fmaf(wv.w, xv.w, dot);
        }
        dot += __shfl_xor(dot, 1);
        dot += __shfl_xor(dot, 2);
        dot += __shfl_xor(dot, 4);
        if (seg == 0) sw[r] = tanhf(dot + bvec[r]);
    }
    __syncthreads();

    // V^T[pos][kg][tid][e] = bf16(sw[kg*8+e] * A[kg*8+e][tid]); 4 coalesced dwordx4
    #pragma unroll
    for (int kg = 0; kg < 4; ++kg) {
        s16x8 pk;
        #pragma unroll
        for (int e = 0; e < 8; ++e) {
            const int k = kg * 8 + e;
            pk[e] = (short)f2bf(sw[k] * A[k * DIM + tid]);
        }
        *(s16x8*)&vt_g[(((size_t)pos * 4 + kg) * DIM + tid) * 8] = pk;
    }
}

// ---------------- Kernel 2: barrier-free G streamer --------------------------
__global__ __launch_bounds__(256) void store_g_kernel(
    const unsigned short* __restrict__ vt_g,
    const float* __restrict__ log_lambda,
    float* __restrict__ out)
{
    __shared__ alignas(16) float stage[4][16 * 128]; // 8KB per wave, 32KB total

    const int tid  = threadIdx.x;
    const int pos  = blockIdx.x;
    const int lane = tid & 63;
    const int rs   = tid >> 6;          // wave: rows 64rs..64rs+63
    const int kg   = lane >> 4, cl = lane & 15;

    // this lane's kg-slab of V^T for this position (L1-resident, 16KB/position)
    const unsigned short* vbase = vt_g + ((size_t)pos * 4 + kg) * DIM * 8;

    s16x8 afr[4]; // row-tile frags (tiles 4rs+t)
    #pragma unroll
    for (int t = 0; t < 4; ++t)
        afr[t] = *(const s16x8*)&vbase[(size_t)((4 * rs + t) * 16 + cl) * 8];

    const float lam = expf(log_lambda[0]);
    const bool on_diag_lane = (kg == (cl >> 2));
    const int  diag_slot    = cl & 3;

    float* sbuf = stage[rs];
    const int wbase = cl * 128 + 4 * kg;   // stage write: row=cl, col=uu*16+4kg
    const int wswz  = (cl & 7) << 2;
    const int rrow0 = lane >> 5;           // stage read: 2 rows / instruction
    const int rcol  = (lane & 31) * 4;

    float* gbase = out + (size_t)pos * DIM * DIM;

    #pragma unroll 1
    for (int t = 0; t < 4; ++t) {
        #pragma unroll 1
        for (int half = 0; half < 2; ++half) {
            s16x8 bfr[8]; // this phase's 8 col-tile frags (static-indexed)
            #pragma unroll
            for (int uu = 0; uu < 8; ++uu) {
                const int u = half * 8 + uu;
                bfr[uu] = *(const s16x8*)&vbase[(size_t)(u * 16 + cl) * 8];
            }
            #pragma unroll
            for (int uu = 0; uu < 8; ++uu) {
                const int u = half * 8 + uu;
                f32x4 acc = (f32x4)(0.f);
                acc = __builtin_amdgcn_mfma_f32_16x16x32_bf16(bfr[uu], afr[t], acc, 0, 0, 0);
                if (u == rs * 4 + t && on_diag_lane) // diagonal tile of G
                    acc[diag_slot] += lam;
                *(f32x4*)&sbuf[(wbase + uu * 16) ^ wswz] = acc;
            }
            #pragma unroll
            for (int m = 0; m < 8; ++m) {
                const int row = 2 * m + rrow0;
                f32x4 v = *(const f32x4*)&sbuf[(row * 128 + rcol) ^ ((row & 7) << 2)];
                float* gp = gbase + (size_t)(rs * 64 + t * 16 + row) * DIM
                                  + half * 128 + rcol;
                __builtin_nontemporal_store(v, (f32x4*)gp);
            }
        }
    }
}

// ---------------- Fallback: R7 monolith (if ws too small) --------------------
__global__ __launch_bounds__(256, 2) void riemannian_metric_fallback(
    const float* __restrict__ x, const float* __restrict__ A,
    const float* __restrict__ log_lambda, const float* __restrict__ W,
    const float* __restrict__ bvec, float* __restrict__ out)
{
    __shared__ float xs[DIM];
    __shared__ float sw[RANK];
    __shared__ alignas(16) unsigned short vt[4][DIM][8];
    __shared__ alignas(16) float stage[4][16 * 128];

    const int tid  = threadIdx.x;
    const int pos  = blockIdx.x;
    const int lane = tid & 63;
    const int rs   = tid >> 6;

    xs[tid] = x[(size_t)pos * DIM + tid];
    __syncthreads();
    {
        const int r = tid >> 3, seg = tid & 7;
        const f32x4* wr4 = (const f32x4*)(W + r * DIM + seg * 32);
        const f32x4* xr4 = (const f32x4*)(xs + seg * 32);
        float dot = 0.f;
        #pragma unroll
        for (int qq = 0; qq < 8; ++qq) {
            f32x4 wv = wr4[qq], xv = xr4[qq];
            dot = fmaf(wv.x, xv.x, dot);
            dot = fmaf(wv.y, xv.y, dot);
            dot = fmaf(wv.z, xv.z, dot);
            dot = fmaf(wv.w, xv.w, dot);
        }
        dot += __shfl_xor(dot, 1);
        dot += __shfl_xor(dot, 2);
        dot += __shfl_xor(dot, 4);
        if (seg == 0) sw[r] = tanhf(dot + bvec[r]);
    }
    __syncthreads();
    #pragma unroll
    for (int g = 0; g < 4; ++g) {
        s16x8 pk;
        #pragma unroll
        for (int e = 0; e < 8; ++e) {
            const int k = g * 8 + e;
            pk[e] = (short)f2bf(sw[k] * A[k * DIM + tid]);
        }
        *(s16x8*)&vt[g][tid][0] = pk;
    }
    __syncthreads();

    const int kg = lane >> 4, cl = lane & 15;
    s16x8 bfr[16];
    #pragma unroll
    for (int u = 0; u < 16; ++u)
        bfr[u] = *(const s16x8*)&vt[kg][u * 16 + cl][0];
    s16x8 afr[4];
    #pragma unroll
    for (int t = 0; t < 4; ++t)
        afr[t] = *(const s16x8*)&vt[kg][rs * 64 + t * 16 + cl][0];

    const float lam = expf(log_lambda[0]);
    const bool on_diag_lane = (kg == (cl >> 2));
    const int  diag_slot    = cl & 3;

    float* sbuf = stage[rs];
    const int wbase = cl * 128 + 4 * kg;
    const int wswz  = (cl & 7) << 2;
    const int rrow0 = lane >> 5;
    const int rcol  = (lane & 31) * 4;
    float* gbase = out + (size_t)pos * DIM * DIM;

    #pragma unroll 1
    for (int t = 0; t < 4; ++t) {
        #pragma unroll 1
        for (int half = 0; half < 2; ++half) {
            #pragma unroll
            for (int uu = 0; uu < 8; ++uu) {
                const int u = half * 8 + uu;
                f32x4 acc = (f32x4)(0.f);
                acc = __builtin_amdgcn_mfma_f32_16x16x32_bf16(bfr[u], afr[t], acc, 0, 0, 0);
                if (u == rs * 4 + t && on_diag_lane)
                    acc[diag_slot] += lam;
                *(f32x4*)&sbuf[(wbase + uu * 16) ^ wswz] = acc;
            }
            #pragma unroll
            for (int m = 0; m < 8; ++m) {
                const int row = 2 * m + rrow0;
                f32x4 v = *(const f32x4*)&sbuf[(row * 128 + rcol) ^ ((row & 7) << 2)];
                float* gp = gbase + (size_t)(rs * 64 + t * 16 + row) * DIM
                                  + half * 128 + rcol;
                __builtin_nontemporal_store(v, (f32x4*)gp);
            }
        }
    }
}

extern "C" void kernel_launch(void* const* d_in, const int* in_sizes, int n_in,
                              void* d_out, int out_size, void* d_ws, size_t ws_size,
                              hipStream_t stream) {
    const float* x          = (const float*)d_in[0];
    const float* A          = (const float*)d_in[1];
    const float* log_lambda = (const float*)d_in[2];
    const float* W          = (const float*)d_in[3];
    const float* bvec       = (const float*)d_in[4];
    float* out              = (float*)d_out;

    const int n_pos = in_sizes[0] / DIM; // B*S = 2048
    const size_t vt_bytes = (size_t)n_pos * 4 * DIM * 8 * sizeof(unsigned short); // 32MB

    if (ws_size >= vt_bytes) {
        unsigned short* vt_g = (unsigned short*)d_ws;
        build_vt_kernel<<<n_pos, 256, 0, stream>>>(x, A, W, bvec, vt_g);
        store_g_kernel<<<n_pos, 256, 0, stream>>>(vt_g, log_lambda, out);
    } else {
        riemannian_metric_fallback<<<n_pos, 256, 0, stream>>>(x, A, log_lambda, W, bvec, out);
    }
}